// Round 18
// baseline (138.860 us; speedup 1.0000x reference)
//
#include <hip/hip_runtime.h>
#include <hip/hip_bf16.h>

// CondConv: B=32, CIN=128, COUT=256, K=3, E=8, H=W=64 -> out [32,256,62,62] fp32
// Pipeline: nhwc(+pool partials) -> route -> combine(bf16 cw) -> implicit-GEMM
//           MFMA conv, 32x32x16 bf16, block 128 x 124 (=2*62 row-aligned;
//           31*124=3844 exact), 4 waves (2Mx2N), acc[2][2] f32x16.
//           R18: K-MAJOR LDS layout [chunk][row][16B] -> 32-lane frag reads
//           are 512B contiguous = ZERO bank conflicts (R17's XOR swizzle was
//           4-way-conflicted for 32-lane chunk-shared reads). No swizzle VALU.
//           B resident per cin-half (32KB), A dbuf 2x16KB, 2 blocks/CU.

#define CC_B    32
#define CC_CIN  128
#define CC_COUT 256
#define CC_NP   3844   // 62*62
#define CC_NT   18     // t = h*9 + t9 : h = cin-half (64), t9 = tap

typedef __attribute__((ext_vector_type(8))) short bf16x8;
typedef __attribute__((ext_vector_type(16))) float f32x16;

// ------------------------------------------------- NHWC cast + pool partials
__global__ void cc_nhwc(const float* __restrict__ x, __hip_bfloat16* __restrict__ xn,
                        float* __restrict__ psum) {
    const int b = blockIdx.x >> 6, y = blockIdx.x & 63;   // 2048 blocks
    __shared__ float lds[64 * 129];                        // [x][cin], +1 pad
    __shared__ float sred[256];
    const int t = threadIdx.x;                             // 256
    const float* src = x + (size_t)b * CC_CIN * 4096 + y * 64;
#pragma unroll
    for (int i = 0; i < 32; ++i) {
        const int idx = i * 256 + t;
        const int cin = idx >> 6, xx = idx & 63;
        lds[xx * 129 + cin] = src[(size_t)cin * 4096 + xx];
    }
    __syncthreads();
    __hip_bfloat16* dst = xn + ((size_t)b * 4096 + y * 64) * CC_CIN;
#pragma unroll
    for (int j = 0; j < 4; ++j) {
        const int cidx = j * 256 + t;                      // 1024 chunks of 8 cin
        const int xx = cidx >> 4, c8 = (cidx & 15) * 8;
        union { __hip_bfloat16 h[8]; uint4 v; } u;
#pragma unroll
        for (int jj = 0; jj < 8; ++jj) u.h[jj] = __float2bfloat16(lds[xx * 129 + c8 + jj]);
        *reinterpret_cast<uint4*>(dst + (size_t)xx * CC_CIN + c8) = u.v;
    }
    const int cin = t & 127, xh = (t >> 7) * 32;
    float s = 0.f;
#pragma unroll
    for (int xx = 0; xx < 32; ++xx) s += lds[(xh + xx) * 129 + cin];
    sred[t] = s;
    __syncthreads();
    if (t < 128) psum[((size_t)b * 64 + y) * CC_CIN + t] = sred[t] + sred[t + 128];
}

// ------------------------------------------------- route: reduce + softmax --
__global__ void cc_route(const float* __restrict__ psum,
                         const float* __restrict__ rw_w,
                         const float* __restrict__ rw_b,
                         float* __restrict__ rweights) {
    const int b = blockIdx.x, c = threadIdx.x;             // 32 blocks x 128
    __shared__ float pl[128];
    __shared__ float lg[8];
    const float* p = psum + (size_t)b * 64 * CC_CIN + c;
    float s = 0.f;
#pragma unroll 8
    for (int y = 0; y < 64; ++y) s += p[(size_t)y * CC_CIN];
    pl[c] = s * (1.f / 4096.f);
    __syncthreads();
    if (c < 8) {
        const float* w = rw_w + c * CC_CIN;
        float a = rw_b[c];
#pragma unroll 8
        for (int i = 0; i < CC_CIN; ++i) a += pl[i] * w[i];
        lg[c] = a;
    }
    __syncthreads();
    if (c == 0) {
        float m = lg[0];
#pragma unroll
        for (int e = 1; e < 8; ++e) m = fmaxf(m, lg[e]);
        float ex[8], sm = 0.f;
#pragma unroll
        for (int e = 0; e < 8; ++e) { ex[e] = __expf(lg[e] - m); sm += ex[e]; }
#pragma unroll
        for (int e = 0; e < 8; ++e) rweights[b * 8 + e] = ex[e] / sm;
    }
}

// -------------------------------------------------------------- combine -----
__global__ void cc_combine(const float* __restrict__ ew,
                           const float* __restrict__ rw,
                           __hip_bfloat16* __restrict__ cw) {
    const int t9 = blockIdx.x >> 8;            // 0..8
    const int cout = blockIdx.x & 255;
    const int cin = threadIdx.x;               // 128 threads
    __shared__ float rws[256];
    rws[cin] = rw[cin];
    rws[cin + 128] = rw[cin + 128];
    __syncthreads();
    float wv[8];
    const size_t base = ((size_t)cout * CC_CIN + cin) * 9 + t9;
#pragma unroll
    for (int e = 0; e < 8; ++e) wv[e] = ew[base + (size_t)e * (CC_COUT * CC_CIN * 9)];
#pragma unroll 4
    for (int b = 0; b < CC_B; ++b) {
        float acc = 0.f;
#pragma unroll
        for (int e = 0; e < 8; ++e) acc += rws[b * 8 + e] * wv[e];
        cw[(((size_t)b * 9 + t9) * CC_COUT + cout) * CC_CIN + cin] = __float2bfloat16(acc);
    }
}

// ----------------------------------------------------------------- conv -----
__device__ __forceinline__ void gload_lds16(const void* g, void* l) {
    __builtin_amdgcn_global_load_lds(
        (const __attribute__((address_space(1))) unsigned int*)g,
        (__attribute__((address_space(3))) unsigned int*)l, 16, 0, 0);
}

// grid 1984, block 256 (4 waves, 2M x 2N). Tile BM=128 x BN=124 (= 2*62).
// K-MAJOR LDS: A tile = 8 planes x [128 rows x 16B] = 16KB (dbuf 2x);
// Bres = 8 planes x [256 rows x 16B] = 32KB @32768 (4 input rows y0..y0+3).
// Staging (rule 21: 1KB contiguous dest, per-lane source):
//   A issue (w,i): plane p=i*2+(w&1), half=w>>1; dest p*2048+half*1024;
//     src row = half*64+lane, chunk p.
//   B issue (w,i): plane i, quarter w; dest i*4096+w*1024;
//     src pixel row = w*64+lane (yy=w, x=lane), chunk i.
// Reads (conflict-free, contiguous 512B per 32-lane group, no swizzle):
//   A: c*2048 + r*16,  r = waveM*64+mf*32+l31, c = ks*2+q2
//   B: c*4096 + row*16, row = pixB[nf]+kyx
// Ledger: A=4 issues/wave; prologue [B(0):8, A(0):4, A(1):4]; open(t) =
// vmcnt(4)+barrier; close = lgkm0+barrier; close(8): stageB(1) then stageA(10).
__global__ __launch_bounds__(256) void cc_conv(
    const __hip_bfloat16* __restrict__ xn,   // [B][64][64][128]
    const __hip_bfloat16* __restrict__ cw,   // [B][9][256][128]
    float* __restrict__ out)                 // [B][256][3844]
{
    __shared__ __align__(16) char smem[65536];
    // ---- XCD-aware decode (bijective over 1984 = 8 xcd x 4 b x 31 nt x 2 mt)
    const int l   = blockIdx.x;
    const int xcd = l & 7, li = l >> 3;          // li in [0,248)
    const int b   = 4 * xcd + li / 62;
    const int r2  = li % 62;
    const int nt  = r2 >> 1, mt = r2 & 1;
    const int m0  = mt * 128;
    const int n0  = nt * 124;                    // = 62*(2*nt): row-aligned
    const int y0  = 2 * nt;                      // input rows y0..y0+3 (<=63)

    const int tid = threadIdx.x;
    const int wid = tid >> 6, lane = tid & 63;   // wid 0..3
    const int waveM = wid >> 1, waveN = wid & 1;

    f32x16 acc[2][2];
#pragma unroll
    for (int i = 0; i < 2; ++i)
#pragma unroll
        for (int j = 0; j < 2; ++j)
#pragma unroll
            for (int v = 0; v < 16; ++v) acc[i][j][v] = 0.f;

    const __hip_bfloat16* cwb = cw + (size_t)b * 9 * CC_COUT * CC_CIN;
    const __hip_bfloat16* xnb = xn + (size_t)b * 4096 * CC_CIN;

    // ---- A staging: issue (w,i) -> plane i*2+(w&1), half w>>1
    const int aRow = (wid >> 1) * 64 + lane;         // source row 0..127
    int laOff[4];
#pragma unroll
    for (int i = 0; i < 4; ++i)
        laOff[i] = (m0 + aRow) * CC_CIN + (i * 2 + (wid & 1)) * 8;
    auto stageA = [&](int t) {
        const int h = t / 9, t9 = t - 9 * h;
        const int aoff = t9 * (CC_COUT * CC_CIN) + h * 64;
        char* Ab = smem + (t & 1) * 16384 + (wid >> 1) * 1024;
#pragma unroll
        for (int i = 0; i < 4; ++i)
            gload_lds16(cwb + aoff + laOff[i], Ab + (i * 2 + (wid & 1)) * 2048);
    };

    // ---- Bres staging: issue (w,i) -> plane i, quarter w (yy=w, x=lane)
    char* Bres = smem + 32768;
    const int lbOff = ((y0 + wid) * 64 + lane) * CC_CIN;   // y0+wid <= 63
    auto stageB = [&](int h) {
        char* Bb = Bres + wid * 1024;
#pragma unroll
        for (int i = 0; i < 8; ++i)
            gload_lds16(xnb + lbOff + i * 8 + h * 64, Bb + i * 4096);
    };

    const int l31 = lane & 31, q2 = lane >> 5;   // 32x32 frag decode

    // per-lane B decode: N-wave owns one output row; pixB = waveN*64 + col
    int pixB[2];
#pragma unroll
    for (int nf = 0; nf < 2; ++nf) {
        int c = nf * 32 + l31;
        if (c > 61) c = 61;                      // col clamp (store-masked)
        pixB[nf] = waveN * 64 + c;
    }

    // prologue queue: [Bres(0):8, A(0):4, A(1):4]
    stageB(0);
    stageA(0);
    stageA(1);

#pragma unroll
    for (int t = 0; t < CC_NT; ++t) {
        const int h = t / 9, t9 = t - 9 * h;
        const int kyx = (t9 / 3) * 64 + (t9 - 3 * (t9 / 3));   // ky*64+kx
        const char* Ab = smem + (t & 1) * 16384;

        // ---- open: own A(t)+Bres(h) retired; A(t+1) stays in flight
        if (t < CC_NT - 1) asm volatile("s_waitcnt vmcnt(4)" ::: "memory");
        else               asm volatile("s_waitcnt vmcnt(0)" ::: "memory");
        asm volatile("s_barrier" ::: "memory");

        // ---- frag reads (K-major, conflict-free) then MFMA burst
        bf16x8 af[2][4], bf[2][4];
#pragma unroll
        for (int ks = 0; ks < 4; ++ks) {
            const int c = ks * 2 + q2;
#pragma unroll
            for (int mf = 0; mf < 2; ++mf) {
                const int r = waveM * 64 + mf * 32 + l31;
                af[mf][ks] = *(const bf16x8*)(Ab + c * 2048 + r * 16);
            }
#pragma unroll
            for (int nf = 0; nf < 2; ++nf) {
                const int row = pixB[nf] + kyx;            // <= 255
                bf[nf][ks] = *(const bf16x8*)(Bres + c * 4096 + row * 16);
            }
        }
        __builtin_amdgcn_s_setprio(1);
#pragma unroll
        for (int ks = 0; ks < 4; ++ks)
#pragma unroll
            for (int mf = 0; mf < 2; ++mf)
#pragma unroll
                for (int nf = 0; nf < 2; ++nf)
                    acc[mf][nf] = __builtin_amdgcn_mfma_f32_32x32x16_bf16(
                        af[mf][ks], bf[nf][ks], acc[mf][nf], 0, 0, 0);
        __builtin_amdgcn_s_setprio(0);

        // ---- close: all LDS reads done before any restage overwrites
        asm volatile("s_waitcnt lgkmcnt(0)" ::: "memory");
        asm volatile("s_barrier" ::: "memory");
        if (t == 8) stageB(1);                   // before A(10): vmcnt(4) drains it
        if (t + 2 < CC_NT) stageA(t + 2);
    }

    // epilogue: 32x32 C/D: col=lane&31, row=(reg&3)+8*(reg>>2)+4*(lane>>5)
#pragma unroll
    for (int mf = 0; mf < 2; ++mf) {
#pragma unroll
        for (int nf = 0; nf < 2; ++nf) {
            const int c2 = nf * 32 + l31;
            if (c2 < 62) {
                const int p = n0 + waveN * 62 + c2;
#pragma unroll
                for (int g = 0; g < 4; ++g) {
                    const int crow = m0 + waveM * 64 + mf * 32 + g * 8 + q2 * 4;
                    const size_t ob = ((size_t)b * CC_COUT + crow) * CC_NP + p;
#pragma unroll
                    for (int j = 0; j < 4; ++j)
                        out[ob + (size_t)j * CC_NP] = acc[mf][nf][g * 4 + j];
                }
            }
        }
    }
}

// ---------------------------------------------------------------- launch ----
extern "C" void kernel_launch(void* const* d_in, const int* in_sizes, int n_in,
                              void* d_out, int out_size, void* d_ws, size_t ws_size,
                              hipStream_t stream) {
    const float* x   = (const float*)d_in[0];
    const float* ew  = (const float*)d_in[1];
    const float* rww = (const float*)d_in[2];
    const float* rwb = (const float*)d_in[3];
    float* out = (float*)d_out;
    char* ws = (char*)d_ws;

    __hip_bfloat16* xnhwc = (__hip_bfloat16*)ws;                    // 33,554,432 B
    __hip_bfloat16* cwcmb = (__hip_bfloat16*)(ws + 33554432);       // 18,874,368 B
    float* psum   = (float*)(ws + 52428800);                        //  1,048,576 B
    float* rwts   = (float*)(ws + 53493760);                        //      1,024 B

    cc_nhwc<<<dim3(CC_B * 64), dim3(256), 0, stream>>>(x, xnhwc, psum);
    cc_route<<<dim3(CC_B), dim3(128), 0, stream>>>(psum, rww, rwb, rwts);
    cc_combine<<<dim3(9 * CC_COUT), dim3(128), 0, stream>>>(ew, rwts, cwcmb);
    cc_conv<<<dim3(1984), dim3(256), 0, stream>>>(xnhwc, cwcmb, out);
}

// Round 19
// 127.265 us; speedup vs baseline: 1.0911x; 1.0911x over previous
//
#include <hip/hip_runtime.h>
#include <hip/hip_bf16.h>

// CondConv: B=32, CIN=128, COUT=256, K=3, E=8, H=W=64 -> out [32,256,62,62] fp32
// Pipeline: nhwc(k-plane xnt[b][k16][yx][8]) -> route -> combine(chunk-major
//           cwk[b][t9][k16][cout][8]) -> implicit-GEMM conv, 32x32x16 bf16.
//           R19: K-major LDS (R18, conflict-free reads) + chunk-major GLOBAL
//           layouts -> staging gather is contiguous 1KB/issue (R18's was
//           256B-strided -> TA-request bound). Transpose absorbed by producers.

#define CC_B    32
#define CC_CIN  128
#define CC_COUT 256
#define CC_NP   3844   // 62*62
#define CC_NT   18     // t = h*9 + t9 : h = cin-half (64), t9 = tap

typedef __attribute__((ext_vector_type(8))) short bf16x8;
typedef __attribute__((ext_vector_type(16))) float f32x16;

// --------------------------------- k-plane-packed cast + pool partials -----
// xnt[b][k8][y][x][8] bf16, k8 = cin/8 (16 planes of 32768 elems)
__global__ void cc_nhwc(const float* __restrict__ x, __hip_bfloat16* __restrict__ xnt,
                        float* __restrict__ psum) {
    const int b = blockIdx.x >> 6, y = blockIdx.x & 63;   // 2048 blocks
    __shared__ float lds[64 * 129];                        // [x][cin], +1 pad
    __shared__ float sred[256];
    const int t = threadIdx.x;                             // 256
    const float* src = x + (size_t)b * CC_CIN * 4096 + y * 64;
#pragma unroll
    for (int i = 0; i < 32; ++i) {
        const int idx = i * 256 + t;
        const int cin = idx >> 6, xx = idx & 63;
        lds[xx * 129 + cin] = src[(size_t)cin * 4096 + xx];
    }
    __syncthreads();
#pragma unroll
    for (int j = 0; j < 4; ++j) {
        const int cidx = j * 256 + t;                      // 1024 chunks of 8 cin
        const int k8 = cidx >> 6, xx = cidx & 63;          // consecutive t -> consecutive xx
        union { __hip_bfloat16 h[8]; uint4 v; } u;
#pragma unroll
        for (int jj = 0; jj < 8; ++jj) u.h[jj] = __float2bfloat16(lds[xx * 129 + k8 * 8 + jj]);
        *reinterpret_cast<uint4*>(xnt + (((size_t)b * 16 + k8) * 4096 + y * 64 + xx) * 8) = u.v;
    }
    const int cin = t & 127, xh = (t >> 7) * 32;
    float s = 0.f;
#pragma unroll
    for (int xx = 0; xx < 32; ++xx) s += lds[(xh + xx) * 129 + cin];
    sred[t] = s;
    __syncthreads();
    if (t < 128) psum[((size_t)b * 64 + y) * CC_CIN + t] = sred[t] + sred[t + 128];
}

// ------------------------------------------------- route: reduce + softmax --
__global__ void cc_route(const float* __restrict__ psum,
                         const float* __restrict__ rw_w,
                         const float* __restrict__ rw_b,
                         float* __restrict__ rweights) {
    const int b = blockIdx.x, c = threadIdx.x;             // 32 blocks x 128
    __shared__ float pl[128];
    __shared__ float lg[8];
    const float* p = psum + (size_t)b * 64 * CC_CIN + c;
    float s = 0.f;
#pragma unroll 8
    for (int y = 0; y < 64; ++y) s += p[(size_t)y * CC_CIN];
    pl[c] = s * (1.f / 4096.f);
    __syncthreads();
    if (c < 8) {
        const float* w = rw_w + c * CC_CIN;
        float a = rw_b[c];
#pragma unroll 8
        for (int i = 0; i < CC_CIN; ++i) a += pl[i] * w[i];
        lg[c] = a;
    }
    __syncthreads();
    if (c == 0) {
        float m = lg[0];
#pragma unroll
        for (int e = 1; e < 8; ++e) m = fmaxf(m, lg[e]);
        float ex[8], sm = 0.f;
#pragma unroll
        for (int e = 0; e < 8; ++e) { ex[e] = __expf(lg[e] - m); sm += ex[e]; }
#pragma unroll
        for (int e = 0; e < 8; ++e) rweights[b * 8 + e] = ex[e] / sm;
    }
}

// -------------------------------------------------------------- combine -----
// cwk[b][t9][k16][cout][8] (bf16) = sum_e rw[b][e]*EW[e][cout][cin][ky][kx]
__global__ void cc_combine(const float* __restrict__ ew,
                           const float* __restrict__ rw,
                           __hip_bfloat16* __restrict__ cwk) {
    const int t9 = blockIdx.x >> 8;            // 0..8
    const int cout = blockIdx.x & 255;
    const int cin = threadIdx.x;               // 128 threads
    __shared__ float rws[256];
    rws[cin] = rw[cin];
    rws[cin + 128] = rw[cin + 128];
    __syncthreads();
    float wv[8];
    const size_t base = ((size_t)cout * CC_CIN + cin) * 9 + t9;
#pragma unroll
    for (int e = 0; e < 8; ++e) wv[e] = ew[base + (size_t)e * (CC_COUT * CC_CIN * 9)];
    const int k8 = cin >> 3, jj = cin & 7;
#pragma unroll 4
    for (int b = 0; b < CC_B; ++b) {
        float acc = 0.f;
#pragma unroll
        for (int e = 0; e < 8; ++e) acc += rws[b * 8 + e] * wv[e];
        cwk[(size_t)b * 294912 + ((t9 * 16 + k8) * 256 + cout) * 8 + jj]
            = __float2bfloat16(acc);
    }
}

// ----------------------------------------------------------------- conv -----
__device__ __forceinline__ void gload_lds16(const void* g, void* l) {
    __builtin_amdgcn_global_load_lds(
        (const __attribute__((address_space(1))) unsigned int*)g,
        (__attribute__((address_space(3))) unsigned int*)l, 16, 0, 0);
}

// grid 1984, block 256 (4 waves, 2M x 2N). Tile BM=128 x BN=124 (= 2*62).
// K-MAJOR LDS: A tile = 8 planes x [128 rows x 16B] = 16KB (dbuf 2x);
// Bres = 8 planes x [256 rows x 16B] = 32KB @32768 (4 input rows y0..y0+3).
// Staging (contiguous 1KB per issue from chunk-major global):
//   A issue (w,i): plane p=i*2+(w&1), half=w>>1; dest p*2048+half*1024;
//     src cwk[t9][h*8+p][m0+half*64+lane][8] -> lane-contiguous 16B.
//   B issue (w,i): plane i, quarter w; dest i*4096+w*1024;
//     src xnt[h*8+i][(y0+w)*64+lane][8] -> lane-contiguous 16B.
// Reads (conflict-free, 512B contiguous per 32-lane group, no swizzle):
//   A: c*2048 + r*16,  r = waveM*64+mf*32+l31, c = ks*2+q2
//   B: c*4096 + row*16, row = pixB[nf]+kyx
// Ledger: A=4 issues/wave; prologue [B(0):8, A(0):4, A(1):4]; open(t) =
// vmcnt(4)+barrier; close = lgkm0+barrier; close(8): stageB(1) then stageA(10).
__global__ __launch_bounds__(256) void cc_conv(
    const __hip_bfloat16* __restrict__ xnt,  // [B][16][4096][8]
    const __hip_bfloat16* __restrict__ cwk,  // [B][9][16][256][8]
    float* __restrict__ out)                 // [B][256][3844]
{
    __shared__ __align__(16) char smem[65536];
    // ---- XCD-aware decode (bijective over 1984 = 8 xcd x 4 b x 31 nt x 2 mt)
    const int l   = blockIdx.x;
    const int xcd = l & 7, li = l >> 3;          // li in [0,248)
    const int b   = 4 * xcd + li / 62;
    const int r2  = li % 62;
    const int nt  = r2 >> 1, mt = r2 & 1;
    const int m0  = mt * 128;
    const int n0  = nt * 124;                    // = 62*(2*nt): row-aligned
    const int y0  = 2 * nt;                      // input rows y0..y0+3 (<=63)

    const int tid = threadIdx.x;
    const int wid = tid >> 6, lane = tid & 63;   // wid 0..3
    const int waveM = wid >> 1, waveN = wid & 1;

    f32x16 acc[2][2];
#pragma unroll
    for (int i = 0; i < 2; ++i)
#pragma unroll
        for (int j = 0; j < 2; ++j)
#pragma unroll
            for (int v = 0; v < 16; ++v) acc[i][j][v] = 0.f;

    const __hip_bfloat16* cwb = cwk + (size_t)b * 294912;   // 9*16*256*8
    const __hip_bfloat16* xnb = xnt + (size_t)b * 524288;   // 16*4096*8

    // ---- A staging: issue (w,i) -> plane p=i*2+(w&1), half=w>>1
    const int aHalf = wid >> 1, aPar = wid & 1;
    auto stageA = [&](int t) {
        const int h = t / 9, t9 = t - 9 * h;
        char* Ab = smem + (t & 1) * 16384 + aHalf * 1024;
#pragma unroll
        for (int i = 0; i < 4; ++i) {
            const int p = i * 2 + aPar;
            gload_lds16(cwb + (((t9 * 16 + h * 8 + p) * 256 + m0 + aHalf * 64 + lane) * 8),
                        Ab + p * 2048);
        }
    };

    // ---- Bres staging: issue (w,i) -> plane i, quarter w (yy=w, x=lane)
    char* Bres = smem + 32768;
    const int bPix = (y0 + wid) * 64 + lane;     // y0+wid <= 63
    auto stageB = [&](int h) {
        char* Bb = Bres + wid * 1024;
#pragma unroll
        for (int i = 0; i < 8; ++i)
            gload_lds16(xnb + (((size_t)(h * 8 + i) * 4096 + bPix) * 8), Bb + i * 4096);
    };

    const int l31 = lane & 31, q2 = lane >> 5;   // 32x32 frag decode

    // per-lane B decode: N-wave owns one output row; pixB = waveN*64 + col
    int pixB[2];
#pragma unroll
    for (int nf = 0; nf < 2; ++nf) {
        int c = nf * 32 + l31;
        if (c > 61) c = 61;                      // col clamp (store-masked)
        pixB[nf] = waveN * 64 + c;
    }

    // prologue queue: [Bres(0):8, A(0):4, A(1):4]
    stageB(0);
    stageA(0);
    stageA(1);

#pragma unroll
    for (int t = 0; t < CC_NT; ++t) {
        const int h = t / 9, t9 = t - 9 * h;
        const int kyx = (t9 / 3) * 64 + (t9 - 3 * (t9 / 3));   // ky*64+kx
        const char* Ab = smem + (t & 1) * 16384;

        // ---- open: own A(t)+Bres(h) retired; A(t+1) stays in flight
        if (t < CC_NT - 1) asm volatile("s_waitcnt vmcnt(4)" ::: "memory");
        else               asm volatile("s_waitcnt vmcnt(0)" ::: "memory");
        asm volatile("s_barrier" ::: "memory");

        // ---- frag reads (K-major, conflict-free) then MFMA burst
        bf16x8 af[2][4], bf[2][4];
#pragma unroll
        for (int ks = 0; ks < 4; ++ks) {
            const int c = ks * 2 + q2;
#pragma unroll
            for (int mf = 0; mf < 2; ++mf) {
                const int r = waveM * 64 + mf * 32 + l31;
                af[mf][ks] = *(const bf16x8*)(Ab + c * 2048 + r * 16);
            }
#pragma unroll
            for (int nf = 0; nf < 2; ++nf) {
                const int row = pixB[nf] + kyx;            // <= 255
                bf[nf][ks] = *(const bf16x8*)(Bres + c * 4096 + row * 16);
            }
        }
        __builtin_amdgcn_s_setprio(1);
#pragma unroll
        for (int ks = 0; ks < 4; ++ks)
#pragma unroll
            for (int mf = 0; mf < 2; ++mf)
#pragma unroll
                for (int nf = 0; nf < 2; ++nf)
                    acc[mf][nf] = __builtin_amdgcn_mfma_f32_32x32x16_bf16(
                        af[mf][ks], bf[nf][ks], acc[mf][nf], 0, 0, 0);
        __builtin_amdgcn_s_setprio(0);

        // ---- close: all LDS reads done before any restage overwrites
        asm volatile("s_waitcnt lgkmcnt(0)" ::: "memory");
        asm volatile("s_barrier" ::: "memory");
        if (t == 8) stageB(1);                   // before A(10): vmcnt(4) drains it
        if (t + 2 < CC_NT) stageA(t + 2);
    }

    // epilogue: 32x32 C/D: col=lane&31, row=(reg&3)+8*(reg>>2)+4*(lane>>5)
#pragma unroll
    for (int mf = 0; mf < 2; ++mf) {
#pragma unroll
        for (int nf = 0; nf < 2; ++nf) {
            const int c2 = nf * 32 + l31;
            if (c2 < 62) {
                const int p = n0 + waveN * 62 + c2;
#pragma unroll
                for (int g = 0; g < 4; ++g) {
                    const int crow = m0 + waveM * 64 + mf * 32 + g * 8 + q2 * 4;
                    const size_t ob = ((size_t)b * CC_COUT + crow) * CC_NP + p;
#pragma unroll
                    for (int j = 0; j < 4; ++j)
                        out[ob + (size_t)j * CC_NP] = acc[mf][nf][g * 4 + j];
                }
            }
        }
    }
}

// ---------------------------------------------------------------- launch ----
extern "C" void kernel_launch(void* const* d_in, const int* in_sizes, int n_in,
                              void* d_out, int out_size, void* d_ws, size_t ws_size,
                              hipStream_t stream) {
    const float* x   = (const float*)d_in[0];
    const float* ew  = (const float*)d_in[1];
    const float* rww = (const float*)d_in[2];
    const float* rwb = (const float*)d_in[3];
    float* out = (float*)d_out;
    char* ws = (char*)d_ws;

    __hip_bfloat16* xnt   = (__hip_bfloat16*)ws;                    // 33,554,432 B
    __hip_bfloat16* cwkb  = (__hip_bfloat16*)(ws + 33554432);       // 18,874,368 B
    float* psum   = (float*)(ws + 52428800);                        //  1,048,576 B
    float* rwts   = (float*)(ws + 53493760);                        //      1,024 B

    cc_nhwc<<<dim3(CC_B * 64), dim3(256), 0, stream>>>(x, xnt, psum);
    cc_route<<<dim3(CC_B), dim3(128), 0, stream>>>(psum, rww, rwb, rwts);
    cc_combine<<<dim3(9 * CC_COUT), dim3(128), 0, stream>>>(ew, rwts, cwkb);
    cc_conv<<<dim3(1984), dim3(256), 0, stream>>>(xnt, cwkb, out);
}